// Round 5
// baseline (2609.327 us; speedup 1.0000x reference)
//
#include <hip/hip_runtime.h>
#include <hip/hip_bf16.h>
#include <math.h>

// Shapes: grd (N=64,C=64,24,24), sat (M=64,C=64,64,64); crop sat[:,:,12:52,12:52] (40x40)
// corr (64,64,17,17); out: [0,4096) similarity f32, [4096,40960) sat_f (64,24,24) f32.
//
// Pipeline: satT/grdT2 bf16 hi-lo transforms -> MFMA implicit-GEMM corr (3-product
// bf16x2, fp32-class accuracy) -> argmax -> sim from corr_max and precomputed norms.

typedef float f32x4 __attribute__((ext_vector_type(4)));
typedef short short8 __attribute__((ext_vector_type(8)));

// ws layout (float words)
#define SATT_HI 0u          // bf16 [m][40*40 pix][64 c]  : 6,553,600 bf16 = 3,276,800 f
#define SATT_LO 3276800u
#define GRDT_HI 6553600u    // bf16 [ij=576][n=64][c=64]  : 2,359,296 bf16 = 1,179,648 f
#define GRDT_LO 7733248u
#define CORR_O  8912896u    // f32 [m][304][64] = 1,245,184 f
#define WIN2_O  10158080u   // f32 [m][289]
#define GN2_O   10176576u   // f32 [64]
#define IDX_O   10176640u   // int [4096]

// ---------- T1: satT hi/lo, channel-last. grid 2560 = (m, r); block 256 ----------
__global__ __launch_bounds__(256) void make_satT(const float* __restrict__ sat,
                                                 __hip_bfloat16* __restrict__ sth,
                                                 __hip_bfloat16* __restrict__ stl) {
    __shared__ __hip_bfloat16 th[40 * 66], tl[40 * 66];
    int m = blockIdx.x / 40, r = blockIdx.x % 40;
    int tid = threadIdx.x;
    const float* base = sat + (size_t)m * 262144 + (12 + r) * 64 + 12;
    for (int k = 0; k < 10; k++) {
        int idx = tid + 256 * k;          // 2560 = 64c * 40w
        int c = idx / 40, w2 = idx % 40;
        float v = base[c * 4096 + w2];
        __hip_bfloat16 h = __float2bfloat16(v);
        __hip_bfloat16 lo = __float2bfloat16(v - __bfloat162float(h));
        th[w2 * 66 + c] = h;
        tl[w2 * 66 + c] = lo;
    }
    __syncthreads();
    __hip_bfloat16* dh = sth + (size_t)m * 102400 + r * 2560;
    __hip_bfloat16* dl = stl + (size_t)m * 102400 + r * 2560;
    for (int k = 0; k < 10; k++) {
        int idx = tid + 256 * k;          // idx = w*64 + c
        int w2 = idx >> 6, c = idx & 63;
        dh[idx] = th[w2 * 66 + c];
        dl[idx] = tl[w2 * 66 + c];
    }
}

// ---------- T2: grdT2 [ij][n][c] hi/lo. grid 256 = (n, c-half, hi/lo); block 256 ----------
__global__ __launch_bounds__(256) void make_grdT(const float* __restrict__ grd,
                                                 __hip_bfloat16* __restrict__ gth,
                                                 __hip_bfloat16* __restrict__ gtl) {
    __shared__ __hip_bfloat16 t[32 * 577];
    int bid = blockIdx.x;
    int n = bid >> 2, ch = (bid >> 1) & 1, hl = bid & 1;
    int tid = threadIdx.x;
    const float* src = grd + (size_t)n * 36864 + ch * 32 * 576;
    for (int k = 0; k < 72; k++) {
        int idx = tid + 256 * k;          // 18432 = 32c * 576ij ; idx = cl*576 + ij
        int cl = idx / 576, ij = idx % 576;
        float v = src[idx];
        __hip_bfloat16 h = __float2bfloat16(v);
        t[cl * 577 + ij] = hl ? __float2bfloat16(v - __bfloat162float(h)) : h;
    }
    __syncthreads();
    __hip_bfloat16* dst = hl ? gtl : gth;
    for (int k = 0; k < 72; k++) {
        int idx = tid + 256 * k;          // idx = ij*32 + cl
        int ij = idx >> 5, cl = idx & 31;
        dst[(size_t)ij * 4096 + n * 64 + ch * 32 + cl] = t[cl * 577 + ij];
    }
}

// ---------- N1: patch-window norms^2 via separable sums. grid 64 (m) ----------
__global__ __launch_bounds__(256) void make_win2(const float* __restrict__ sat,
                                                 float* __restrict__ win2) {
    __shared__ float S2[40][41];
    __shared__ float RS[40][18];
    int m = blockIdx.x, tid = threadIdx.x;
    const float* base = sat + (size_t)m * 262144;
    for (int k = 0; k < 7; k++) {
        int idx = tid + 256 * k;
        if (idx < 1600) {
            int r = idx / 40, w2 = idx % 40;
            float s = 0.0f;
            for (int c = 0; c < 64; c++) {
                float v = base[c * 4096 + (12 + r) * 64 + 12 + w2];
                s += v * v;
            }
            S2[r][w2] = s;
        }
    }
    __syncthreads();
    for (int k = 0; k < 3; k++) {
        int idx = tid + 256 * k;
        if (idx < 680) {
            int r = idx / 17, x = idx % 17;
            float s = 0.0f;
            for (int j = 0; j < 24; j++) s += S2[r][x + j];
            RS[r][x] = s;
        }
    }
    __syncthreads();
    for (int k = 0; k < 2; k++) {
        int idx = tid + 256 * k;
        if (idx < 289) {
            int y = idx / 17, x = idx % 17;
            float s = 0.0f;
            for (int i2 = 0; i2 < 24; i2++) s += RS[y + i2][x];
            win2[m * 289 + idx] = s;
        }
    }
}

// ---------- N2: ||grd_n||^2. grid 64 (n) ----------
__global__ __launch_bounds__(256) void make_gn2(const float* __restrict__ grd,
                                                float* __restrict__ gn2) {
    int n = blockIdx.x, tid = threadIdx.x;
    const float* g = grd + (size_t)n * 36864;
    float s = 0.0f;
    for (int k = 0; k < 144; k++) {
        float v = g[tid + 256 * k];
        s += v * v;
    }
    for (int off = 32; off; off >>= 1) s += __shfl_down(s, off);
    __shared__ float red[4];
    if ((tid & 63) == 0) red[tid >> 6] = s;
    __syncthreads();
    if (tid == 0) gn2[n] = red[0] + red[1] + red[2] + red[3];
}

// ---------- K1: MFMA corr. grid 256 = (m, iq); block 256 = 4 waves ----------
// Wave w owns p-tiles {w,4+w,8+w,12+w,16+w(<19)} x 4 n-tiles. K = c (2x32), x (i,j) in
// i-range [6iq,6iq+6). bf16x2: acc += ah*bh + ah*bl + al*bh.
__global__ __launch_bounds__(256, 1) void corr_mfma(const __hip_bfloat16* __restrict__ sth,
                                                    const __hip_bfloat16* __restrict__ stl,
                                                    const __hip_bfloat16* __restrict__ gth,
                                                    const __hip_bfloat16* __restrict__ gtl,
                                                    float* __restrict__ corr) {
    __shared__ __align__(16) __hip_bfloat16 B[2][2][64 * 72];  // [buf][h/l][n*72+c], 72-pad
    int bid = blockIdx.x;
    int m = bid >> 2, iq = bid & 3;
    int tid = threadIdx.x;
    int w = tid >> 6, l = tid & 63, r = l & 15, g = l >> 4;
    int T = (w < 3) ? 5 : 4;

    int rowbase[5];
    for (int k = 0; k < 5; k++) {
        int p = 16 * (w + 4 * k) + r;
        if (p > 288) p = 288;                 // clamp pad rows to a valid pixel
        rowbase[k] = (p / 17) * 40 + (p % 17);
    }
    f32x4 acc[5][4];
    for (int k = 0; k < 5; k++)
        for (int nt = 0; nt < 4; nt++) acc[k][nt] = (f32x4)0.0f;

    const __hip_bfloat16* sh = sth + (size_t)m * 102400;
    const __hip_bfloat16* sl = stl + (size_t)m * 102400;
    int stn = tid >> 2, stc = (tid & 3) * 16;  // staging dest (n, c0)

#define STAGE(buf, ijl) {                                                        \
        int ijg = 144 * iq + (ijl);                                              \
        const float4* s_h = (const float4*)(gth + (size_t)ijg * 4096 + tid * 16);\
        const float4* s_l = (const float4*)(gtl + (size_t)ijg * 4096 + tid * 16);\
        float4 vh0 = s_h[0], vh1 = s_h[1], vl0 = s_l[0], vl1 = s_l[1];           \
        float4* dH = (float4*)&B[buf][0][stn * 72 + stc];                        \
        float4* dL = (float4*)&B[buf][1][stn * 72 + stc];                        \
        dH[0] = vh0; dH[1] = vh1; dL[0] = vl0; dL[1] = vl1;                      \
    }

    STAGE(0, 0);
    __syncthreads();

    for (int ijl = 0; ijl < 144; ijl++) {
        int buf = ijl & 1;
        if (ijl + 1 < 144) STAGE(buf ^ 1, ijl + 1);

        int pixoff = (6 * iq + ijl / 24) * 40 + (ijl % 24);  // i*40 + j

        short8 ah[5][2], al[5][2];
        for (int k = 0; k < T; k++) {
            size_t e = (size_t)(rowbase[k] + pixoff) * 64 + g * 8;
            ah[k][0] = *(const short8*)(sh + e);
            ah[k][1] = *(const short8*)(sh + e + 32);
            al[k][0] = *(const short8*)(sl + e);
            al[k][1] = *(const short8*)(sl + e + 32);
        }
        for (int cc = 0; cc < 2; cc++) {
            short8 bh[4], bl[4];
            for (int nt = 0; nt < 4; nt++) {
                int off = (nt * 16 + r) * 72 + cc * 32 + g * 8;
                bh[nt] = *(const short8*)&B[buf][0][off];
                bl[nt] = *(const short8*)&B[buf][1][off];
            }
            for (int k = 0; k < T; k++)
                for (int nt = 0; nt < 4; nt++) {
                    acc[k][nt] = __builtin_amdgcn_mfma_f32_16x16x32_bf16(ah[k][cc], bh[nt], acc[k][nt], 0, 0, 0);
                    acc[k][nt] = __builtin_amdgcn_mfma_f32_16x16x32_bf16(ah[k][cc], bl[nt], acc[k][nt], 0, 0, 0);
                    acc[k][nt] = __builtin_amdgcn_mfma_f32_16x16x32_bf16(al[k][cc], bh[nt], acc[k][nt], 0, 0, 0);
                }
        }
        __syncthreads();
    }

    for (int k = 0; k < T; k++) {
        int tile = w + 4 * k;
        for (int nt = 0; nt < 4; nt++)
            for (int reg = 0; reg < 4; reg++) {
                int prow = 16 * tile + 4 * g + reg;
                if (prow < 289)
                    atomicAdd(&corr[((size_t)m * 304 + prow) * 64 + nt * 16 + r],
                              acc[k][nt][reg]);
            }
    }
#undef STAGE
}

// ---------- K2: argmax + similarity. grid 4096 = (m,n); block 64 ----------
__global__ __launch_bounds__(64) void argsim(const float* __restrict__ corr,
                                             const float* __restrict__ win2,
                                             const float* __restrict__ gn2,
                                             float* __restrict__ out,
                                             int* __restrict__ idxb) {
    int b = blockIdx.x, m = b >> 6, n = b & 63, lane = threadIdx.x;
    float bv = -3.0e38f;
    int bi = 1 << 30;
    for (int k = 0; k < 5; k++) {
        int p = lane + 64 * k;
        if (p < 289) {
            float v = corr[((size_t)m * 304 + p) * 64 + n];
            if (v > bv) { bv = v; bi = p; }   // ascending p: strict > = first occurrence
        }
    }
    for (int off = 32; off; off >>= 1) {
        float ov = __shfl_down(bv, off);
        int oi = __shfl_down(bi, off);
        if (ov > bv || (ov == bv && oi < bi)) { bv = ov; bi = oi; }
    }
    if (lane == 0) {
        float np = sqrtf(win2[m * 289 + bi]);
        float ng = sqrtf(gn2[n]);
        out[b] = bv / (fmaxf(np, 1e-12f) * fmaxf(ng, 1e-12f));
        idxb[b] = bi;
    }
}

// ---------- K3: winning patch for (63,63). grid 144; block 256 ----------
__global__ __launch_bounds__(256) void copy_patch(const float* __restrict__ sat,
                                                  const int* __restrict__ idxb,
                                                  float* __restrict__ out) {
    int fidx = idxb[4095];
    int hy = fidx / 17, wx = fidx % 17;
    int e = blockIdx.x * 256 + threadIdx.x;   // < 36864
    int c = e / 576;
    int rem = e - c * 576;
    int rr = rem / 24, col = rem - rr * 24;
    out[4096 + e] = sat[(size_t)(63 * 64 + c) * 4096 + (12 + hy + rr) * 64 + 12 + wx + col];
}

extern "C" void kernel_launch(void* const* d_in, const int* in_sizes, int n_in,
                              void* d_out, int out_size, void* d_ws, size_t ws_size,
                              hipStream_t stream) {
    const float* grd = (const float*)d_in[0];
    const float* sat = (const float*)d_in[1];
    float* out = (float*)d_out;

    float* wsf = (float*)d_ws;
    __hip_bfloat16* sth = (__hip_bfloat16*)(wsf + SATT_HI);
    __hip_bfloat16* stl = (__hip_bfloat16*)(wsf + SATT_LO);
    __hip_bfloat16* gth = (__hip_bfloat16*)(wsf + GRDT_HI);
    __hip_bfloat16* gtl = (__hip_bfloat16*)(wsf + GRDT_LO);
    float* corr = wsf + CORR_O;
    float* win2 = wsf + WIN2_O;
    float* gn2  = wsf + GN2_O;
    int*   idxb = (int*)(wsf + IDX_O);

    hipMemsetAsync(corr, 0, (size_t)64 * 304 * 64 * sizeof(float), stream);
    make_satT<<<2560, 256, 0, stream>>>(sat, sth, stl);
    make_grdT<<<256, 256, 0, stream>>>(grd, gth, gtl);
    make_win2<<<64, 256, 0, stream>>>(sat, win2);
    make_gn2<<<64, 256, 0, stream>>>(grd, gn2);
    corr_mfma<<<256, 256, 0, stream>>>(sth, stl, gth, gtl, corr);
    argsim<<<4096, 64, 0, stream>>>(corr, win2, gn2, out, idxb);
    copy_patch<<<144, 256, 0, stream>>>(sat, idxb, out);
}

// Round 6
// 474.293 us; speedup vs baseline: 5.5015x; 5.5015x over previous
//
#include <hip/hip_runtime.h>
#include <hip/hip_bf16.h>
#include <math.h>

// Shapes: grd (N=64,C=64,24,24), sat (M=64,C=64,64,64); crop sat[:,:,12:52,12:52] (40x40)
// corr (64,64,17,17); out: [0,4096) similarity f32, [4096,40960) sat_f (64,24,24) f32.
//
// Pipeline: satT/grdT2 bf16 hi-lo transforms -> MFMA implicit-GEMM corr (3-product
// bf16x2, fp32-class accuracy) -> argmax -> sim from corr_max and precomputed norms.

typedef float f32x4 __attribute__((ext_vector_type(4)));
typedef short short8 __attribute__((ext_vector_type(8)));

// ws layout (float words)
#define SATT_HI 0u          // bf16 [m][40*40 pix][64 c]  : 6,553,600 bf16 = 3,276,800 f
#define SATT_LO 3276800u
#define GRDT_HI 6553600u    // bf16 [ij=576][n=64][c=64]  : 2,359,296 bf16 = 1,179,648 f
#define GRDT_LO 7733248u
#define CORR_O  8912896u    // f32 [m][304][64] = 1,245,184 f
#define WIN2_O  10158080u   // f32 [m][289]
#define GN2_O   10176576u   // f32 [64]
#define IDX_O   10176640u   // int [4096]

// ---------- T1: satT hi/lo, channel-last. grid 2560 = (m, r); block 256 ----------
__global__ __launch_bounds__(256) void make_satT(const float* __restrict__ sat,
                                                 __hip_bfloat16* __restrict__ sth,
                                                 __hip_bfloat16* __restrict__ stl) {
    __shared__ __hip_bfloat16 th[40 * 66], tl[40 * 66];
    int m = blockIdx.x / 40, r = blockIdx.x % 40;
    int tid = threadIdx.x;
    const float* base = sat + (size_t)m * 262144 + (12 + r) * 64 + 12;
    for (int k = 0; k < 10; k++) {
        int idx = tid + 256 * k;          // 2560 = 64c * 40w
        int c = idx / 40, w2 = idx % 40;
        float v = base[c * 4096 + w2];
        __hip_bfloat16 h = __float2bfloat16(v);
        __hip_bfloat16 lo = __float2bfloat16(v - __bfloat162float(h));
        th[w2 * 66 + c] = h;
        tl[w2 * 66 + c] = lo;
    }
    __syncthreads();
    __hip_bfloat16* dh = sth + (size_t)m * 102400 + r * 2560;
    __hip_bfloat16* dl = stl + (size_t)m * 102400 + r * 2560;
    for (int k = 0; k < 10; k++) {
        int idx = tid + 256 * k;          // idx = w*64 + c
        int w2 = idx >> 6, c = idx & 63;
        dh[idx] = th[w2 * 66 + c];
        dl[idx] = tl[w2 * 66 + c];
    }
}

// ---------- T2: grdT2 [ij][n][c] hi/lo. grid 256 = (n, c-half, hi/lo); block 256 ----------
__global__ __launch_bounds__(256) void make_grdT(const float* __restrict__ grd,
                                                 __hip_bfloat16* __restrict__ gth,
                                                 __hip_bfloat16* __restrict__ gtl) {
    __shared__ __hip_bfloat16 t[32 * 577];
    int bid = blockIdx.x;
    int n = bid >> 2, ch = (bid >> 1) & 1, hl = bid & 1;
    int tid = threadIdx.x;
    const float* src = grd + (size_t)n * 36864 + ch * 32 * 576;
    for (int k = 0; k < 72; k++) {
        int idx = tid + 256 * k;          // 18432 = 32c * 576ij ; idx = cl*576 + ij
        int cl = idx / 576, ij = idx % 576;
        float v = src[idx];
        __hip_bfloat16 h = __float2bfloat16(v);
        t[cl * 577 + ij] = hl ? __float2bfloat16(v - __bfloat162float(h)) : h;
    }
    __syncthreads();
    __hip_bfloat16* dst = hl ? gtl : gth;
    for (int k = 0; k < 72; k++) {
        int idx = tid + 256 * k;          // idx = ij*32 + cl
        int ij = idx >> 5, cl = idx & 31;
        dst[(size_t)ij * 4096 + n * 64 + ch * 32 + cl] = t[cl * 577 + ij];
    }
}

// ---------- N1: patch-window norms^2 via separable sums. grid 64 (m) ----------
__global__ __launch_bounds__(256) void make_win2(const float* __restrict__ sat,
                                                 float* __restrict__ win2) {
    __shared__ float S2[40][41];
    __shared__ float RS[40][18];
    int m = blockIdx.x, tid = threadIdx.x;
    const float* base = sat + (size_t)m * 262144;
    for (int k = 0; k < 7; k++) {
        int idx = tid + 256 * k;
        if (idx < 1600) {
            int r = idx / 40, w2 = idx % 40;
            float s = 0.0f;
            for (int c = 0; c < 64; c++) {
                float v = base[c * 4096 + (12 + r) * 64 + 12 + w2];
                s += v * v;
            }
            S2[r][w2] = s;
        }
    }
    __syncthreads();
    for (int k = 0; k < 3; k++) {
        int idx = tid + 256 * k;
        if (idx < 680) {
            int r = idx / 17, x = idx % 17;
            float s = 0.0f;
            for (int j = 0; j < 24; j++) s += S2[r][x + j];
            RS[r][x] = s;
        }
    }
    __syncthreads();
    for (int k = 0; k < 2; k++) {
        int idx = tid + 256 * k;
        if (idx < 289) {
            int y = idx / 17, x = idx % 17;
            float s = 0.0f;
            for (int i2 = 0; i2 < 24; i2++) s += RS[y + i2][x];
            win2[m * 289 + idx] = s;
        }
    }
}

// ---------- N2: ||grd_n||^2. grid 64 (n) ----------
__global__ __launch_bounds__(256) void make_gn2(const float* __restrict__ grd,
                                                float* __restrict__ gn2) {
    int n = blockIdx.x, tid = threadIdx.x;
    const float* g = grd + (size_t)n * 36864;
    float s = 0.0f;
    for (int k = 0; k < 144; k++) {
        float v = g[tid + 256 * k];
        s += v * v;
    }
    for (int off = 32; off; off >>= 1) s += __shfl_down(s, off);
    __shared__ float red[4];
    if ((tid & 63) == 0) red[tid >> 6] = s;
    __syncthreads();
    if (tid == 0) gn2[n] = red[0] + red[1] + red[2] + red[3];
}

// ---------- K1: MFMA corr. grid 256; block 256 = 4 waves ----------
// XCD-aware mapping (dispatch round-robins bid across 8 XCDs): all 32 blocks on an
// XCD share 8 m's -> satT working set (8 x 400 KB) is L2-resident; the 4 iq-blocks
// of each m land on the same XCD -> atomic lines stay cache-local.
// Wave w owns p-tiles {w, 4+w, 8+w, 12+w, 16+w} x 4 n-tiles. Tile 19 (wave 3, k=4)
// is a ghost: loads clamp to p=288, stores are guarded by prow<289. T=5 is
// COMPILE-TIME so all fragment arrays fully unroll into registers (the previous
// runtime T=(w<3)?5:4 sent ah/al/acc to scratch: 8.4 GB of spill traffic).
// bf16x2 split: acc += ah*bh + ah*bl + al*bh.
__global__ __launch_bounds__(256, 1) void corr_mfma(const __hip_bfloat16* __restrict__ sth,
                                                    const __hip_bfloat16* __restrict__ stl,
                                                    const __hip_bfloat16* __restrict__ gth,
                                                    const __hip_bfloat16* __restrict__ gtl,
                                                    float* __restrict__ corr) {
    __shared__ __align__(16) __hip_bfloat16 B[2][2][64 * 72];  // [buf][h/l][n*72+c], 72-pad
    int bid = blockIdx.x;
    int xcd = bid & 7, slot = bid >> 3;            // slot 0..31
    int m = xcd * 8 + (slot >> 2), iq = slot & 3;  // 8 m per XCD, 4 iq per m
    int tid = threadIdx.x;
    int w = tid >> 6, l = tid & 63, r = l & 15, g = l >> 4;

    int rowbase[5];
#pragma unroll
    for (int k = 0; k < 5; k++) {
        int p = 16 * (w + 4 * k) + r;
        if (p > 288) p = 288;                 // ghost rows read a valid pixel
        rowbase[k] = (p / 17) * 40 + (p % 17);
    }
    f32x4 acc[5][4];
#pragma unroll
    for (int k = 0; k < 5; k++)
#pragma unroll
        for (int nt = 0; nt < 4; nt++) acc[k][nt] = (f32x4)0.0f;

    const __hip_bfloat16* sh = sth + (size_t)m * 102400;
    const __hip_bfloat16* sl = stl + (size_t)m * 102400;
    int stn = tid >> 2, stc = (tid & 3) * 16;  // staging dest (n, c0)

#define STAGE(buf, ijl) {                                                        \
        int ijg = 144 * iq + (ijl);                                              \
        const float4* s_h = (const float4*)(gth + (size_t)ijg * 4096 + tid * 16);\
        const float4* s_l = (const float4*)(gtl + (size_t)ijg * 4096 + tid * 16);\
        float4 vh0 = s_h[0], vh1 = s_h[1], vl0 = s_l[0], vl1 = s_l[1];           \
        float4* dH = (float4*)&B[buf][0][stn * 72 + stc];                        \
        float4* dL = (float4*)&B[buf][1][stn * 72 + stc];                        \
        dH[0] = vh0; dH[1] = vh1; dL[0] = vl0; dL[1] = vl1;                      \
    }

    STAGE(0, 0);
    __syncthreads();

    for (int ijl = 0; ijl < 144; ijl++) {
        int buf = ijl & 1;
        if (ijl + 1 < 144) STAGE(buf ^ 1, ijl + 1);

        int pixoff = (6 * iq + ijl / 24) * 40 + (ijl % 24);  // i*40 + j

        short8 ah[5][2], al[5][2];
#pragma unroll
        for (int k = 0; k < 5; k++) {
            size_t e = (size_t)(rowbase[k] + pixoff) * 64 + g * 8;
            ah[k][0] = *(const short8*)(sh + e);
            ah[k][1] = *(const short8*)(sh + e + 32);
            al[k][0] = *(const short8*)(sl + e);
            al[k][1] = *(const short8*)(sl + e + 32);
        }
#pragma unroll
        for (int cc = 0; cc < 2; cc++) {
            short8 bh[4], bl[4];
#pragma unroll
            for (int nt = 0; nt < 4; nt++) {
                int off = (nt * 16 + r) * 72 + cc * 32 + g * 8;
                bh[nt] = *(const short8*)&B[buf][0][off];
                bl[nt] = *(const short8*)&B[buf][1][off];
            }
#pragma unroll
            for (int k = 0; k < 5; k++)
#pragma unroll
                for (int nt = 0; nt < 4; nt++) {
                    acc[k][nt] = __builtin_amdgcn_mfma_f32_16x16x32_bf16(ah[k][cc], bh[nt], acc[k][nt], 0, 0, 0);
                    acc[k][nt] = __builtin_amdgcn_mfma_f32_16x16x32_bf16(ah[k][cc], bl[nt], acc[k][nt], 0, 0, 0);
                    acc[k][nt] = __builtin_amdgcn_mfma_f32_16x16x32_bf16(al[k][cc], bh[nt], acc[k][nt], 0, 0, 0);
                }
        }
        __syncthreads();
    }

#pragma unroll
    for (int k = 0; k < 5; k++) {
        int tile = w + 4 * k;
#pragma unroll
        for (int nt = 0; nt < 4; nt++)
#pragma unroll
            for (int reg = 0; reg < 4; reg++) {
                int prow = 16 * tile + 4 * g + reg;
                if (prow < 289)
                    atomicAdd(&corr[((size_t)m * 304 + prow) * 64 + nt * 16 + r],
                              acc[k][nt][reg]);
            }
    }
#undef STAGE
}

// ---------- K2: argmax + similarity. grid 4096 = (m,n); block 64 ----------
__global__ __launch_bounds__(64) void argsim(const float* __restrict__ corr,
                                             const float* __restrict__ win2,
                                             const float* __restrict__ gn2,
                                             float* __restrict__ out,
                                             int* __restrict__ idxb) {
    int b = blockIdx.x, m = b >> 6, n = b & 63, lane = threadIdx.x;
    float bv = -3.0e38f;
    int bi = 1 << 30;
    for (int k = 0; k < 5; k++) {
        int p = lane + 64 * k;
        if (p < 289) {
            float v = corr[((size_t)m * 304 + p) * 64 + n];
            if (v > bv) { bv = v; bi = p; }   // ascending p: strict > = first occurrence
        }
    }
    for (int off = 32; off; off >>= 1) {
        float ov = __shfl_down(bv, off);
        int oi = __shfl_down(bi, off);
        if (ov > bv || (ov == bv && oi < bi)) { bv = ov; bi = oi; }
    }
    if (lane == 0) {
        float np = sqrtf(win2[m * 289 + bi]);
        float ng = sqrtf(gn2[n]);
        out[b] = bv / (fmaxf(np, 1e-12f) * fmaxf(ng, 1e-12f));
        idxb[b] = bi;
    }
}

// ---------- K3: winning patch for (63,63). grid 144; block 256 ----------
__global__ __launch_bounds__(256) void copy_patch(const float* __restrict__ sat,
                                                  const int* __restrict__ idxb,
                                                  float* __restrict__ out) {
    int fidx = idxb[4095];
    int hy = fidx / 17, wx = fidx % 17;
    int e = blockIdx.x * 256 + threadIdx.x;   // < 36864
    int c = e / 576;
    int rem = e - c * 576;
    int rr = rem / 24, col = rem - rr * 24;
    out[4096 + e] = sat[(size_t)(63 * 64 + c) * 4096 + (12 + hy + rr) * 64 + 12 + wx + col];
}

extern "C" void kernel_launch(void* const* d_in, const int* in_sizes, int n_in,
                              void* d_out, int out_size, void* d_ws, size_t ws_size,
                              hipStream_t stream) {
    const float* grd = (const float*)d_in[0];
    const float* sat = (const float*)d_in[1];
    float* out = (float*)d_out;

    float* wsf = (float*)d_ws;
    __hip_bfloat16* sth = (__hip_bfloat16*)(wsf + SATT_HI);
    __hip_bfloat16* stl = (__hip_bfloat16*)(wsf + SATT_LO);
    __hip_bfloat16* gth = (__hip_bfloat16*)(wsf + GRDT_HI);
    __hip_bfloat16* gtl = (__hip_bfloat16*)(wsf + GRDT_LO);
    float* corr = wsf + CORR_O;
    float* win2 = wsf + WIN2_O;
    float* gn2  = wsf + GN2_O;
    int*   idxb = (int*)(wsf + IDX_O);

    hipMemsetAsync(corr, 0, (size_t)64 * 304 * 64 * sizeof(float), stream);
    make_satT<<<2560, 256, 0, stream>>>(sat, sth, stl);
    make_grdT<<<256, 256, 0, stream>>>(grd, gth, gtl);
    make_win2<<<64, 256, 0, stream>>>(sat, win2);
    make_gn2<<<64, 256, 0, stream>>>(grd, gn2);
    corr_mfma<<<256, 256, 0, stream>>>(sth, stl, gth, gtl, corr);
    argsim<<<4096, 64, 0, stream>>>(corr, win2, gn2, out, idxb);
    copy_patch<<<144, 256, 0, stream>>>(sat, idxb, out);
}

// Round 7
// 412.334 us; speedup vs baseline: 6.3282x; 1.1503x over previous
//
#include <hip/hip_runtime.h>
#include <hip/hip_bf16.h>
#include <math.h>

// Shapes: grd (N=64,C=64,24,24), sat (M=64,C=64,64,64); crop sat[:,:,12:52,12:52] (40x40)
// corr (64,64,17,17); out: [0,4096) similarity f32, [4096,40960) sat_f (64,24,24) f32.
//
// Pipeline: satT/grdT2 bf16 hi-lo transforms -> MFMA implicit-GEMM corr (3-product
// bf16x2, fp32-class accuracy) -> argmax -> sim from corr_max and precomputed norms.

typedef float f32x4 __attribute__((ext_vector_type(4)));
typedef short short8 __attribute__((ext_vector_type(8)));

// ws layout (float words)
#define SATT_HI 0u          // bf16 [m][40*40 pix][64 c]  : 6,553,600 bf16 = 3,276,800 f
#define SATT_LO 3276800u
#define GRDT_HI 6553600u    // bf16 [ij=576][n=64][c=64]  : 2,359,296 bf16 = 1,179,648 f
#define GRDT_LO 7733248u
#define CORR_O  8912896u    // f32 [m][304][64] = 1,245,184 f
#define WIN2_O  10158080u   // f32 [m][289]
#define GN2_O   10176576u   // f32 [64]
#define IDX_O   10176640u   // int [4096]

// ---------- T1: satT hi/lo, channel-last. grid 2560 = (m, r); block 256 ----------
__global__ __launch_bounds__(256) void make_satT(const float* __restrict__ sat,
                                                 __hip_bfloat16* __restrict__ sth,
                                                 __hip_bfloat16* __restrict__ stl) {
    __shared__ __hip_bfloat16 th[40 * 66], tl[40 * 66];
    int m = blockIdx.x / 40, r = blockIdx.x % 40;
    int tid = threadIdx.x;
    const float* base = sat + (size_t)m * 262144 + (12 + r) * 64 + 12;
    for (int k = 0; k < 10; k++) {
        int idx = tid + 256 * k;          // 2560 = 64c * 40w
        int c = idx / 40, w2 = idx % 40;
        float v = base[c * 4096 + w2];
        __hip_bfloat16 h = __float2bfloat16(v);
        __hip_bfloat16 lo = __float2bfloat16(v - __bfloat162float(h));
        th[w2 * 66 + c] = h;
        tl[w2 * 66 + c] = lo;
    }
    __syncthreads();
    __hip_bfloat16* dh = sth + (size_t)m * 102400 + r * 2560;
    __hip_bfloat16* dl = stl + (size_t)m * 102400 + r * 2560;
    for (int k = 0; k < 10; k++) {
        int idx = tid + 256 * k;          // idx = w*64 + c
        int w2 = idx >> 6, c = idx & 63;
        dh[idx] = th[w2 * 66 + c];
        dl[idx] = tl[w2 * 66 + c];
    }
}

// ---------- T2: grdT2 [ij][n][c] hi/lo. grid 256 = (n, c-half, hi/lo); block 256 ----------
__global__ __launch_bounds__(256) void make_grdT(const float* __restrict__ grd,
                                                 __hip_bfloat16* __restrict__ gth,
                                                 __hip_bfloat16* __restrict__ gtl) {
    __shared__ __hip_bfloat16 t[32 * 577];
    int bid = blockIdx.x;
    int n = bid >> 2, ch = (bid >> 1) & 1, hl = bid & 1;
    int tid = threadIdx.x;
    const float* src = grd + (size_t)n * 36864 + ch * 32 * 576;
    for (int k = 0; k < 72; k++) {
        int idx = tid + 256 * k;          // 18432 = 32c * 576ij ; idx = cl*576 + ij
        int cl = idx / 576, ij = idx % 576;
        float v = src[idx];
        __hip_bfloat16 h = __float2bfloat16(v);
        t[cl * 577 + ij] = hl ? __float2bfloat16(v - __bfloat162float(h)) : h;
    }
    __syncthreads();
    __hip_bfloat16* dst = hl ? gtl : gth;
    for (int k = 0; k < 72; k++) {
        int idx = tid + 256 * k;          // idx = ij*32 + cl
        int ij = idx >> 5, cl = idx & 31;
        dst[(size_t)ij * 4096 + n * 64 + ch * 32 + cl] = t[cl * 577 + ij];
    }
}

// ---------- N1: patch-window norms^2 via separable sums. grid 64 (m) ----------
__global__ __launch_bounds__(256) void make_win2(const float* __restrict__ sat,
                                                 float* __restrict__ win2) {
    __shared__ float S2[40][41];
    __shared__ float RS[40][18];
    int m = blockIdx.x, tid = threadIdx.x;
    const float* base = sat + (size_t)m * 262144;
    for (int k = 0; k < 7; k++) {
        int idx = tid + 256 * k;
        if (idx < 1600) {
            int r = idx / 40, w2 = idx % 40;
            float s = 0.0f;
            for (int c = 0; c < 64; c++) {
                float v = base[c * 4096 + (12 + r) * 64 + 12 + w2];
                s += v * v;
            }
            S2[r][w2] = s;
        }
    }
    __syncthreads();
    for (int k = 0; k < 3; k++) {
        int idx = tid + 256 * k;
        if (idx < 680) {
            int r = idx / 17, x = idx % 17;
            float s = 0.0f;
            for (int j = 0; j < 24; j++) s += S2[r][x + j];
            RS[r][x] = s;
        }
    }
    __syncthreads();
    for (int k = 0; k < 2; k++) {
        int idx = tid + 256 * k;
        if (idx < 289) {
            int y = idx / 17, x = idx % 17;
            float s = 0.0f;
            for (int i2 = 0; i2 < 24; i2++) s += RS[y + i2][x];
            win2[m * 289 + idx] = s;
        }
    }
}

// ---------- N2: ||grd_n||^2. grid 64 (n) ----------
__global__ __launch_bounds__(256) void make_gn2(const float* __restrict__ grd,
                                                float* __restrict__ gn2) {
    int n = blockIdx.x, tid = threadIdx.x;
    const float* g = grd + (size_t)n * 36864;
    float s = 0.0f;
    for (int k = 0; k < 144; k++) {
        float v = g[tid + 256 * k];
        s += v * v;
    }
    for (int off = 32; off; off >>= 1) s += __shfl_down(s, off);
    __shared__ float red[4];
    if ((tid & 63) == 0) red[tid >> 6] = s;
    __syncthreads();
    if (tid == 0) gn2[n] = red[0] + red[1] + red[2] + red[3];
}

// ---------- K1: MFMA corr. grid 512; block 256 = 4 waves; 2 blocks/CU ----------
// Round-5 post-mortem: 1 block/CU = 1 wave/SIMD left the MFMA pipe idle 72% of the
// time (MfmaUtil 27.7%, busy-time == theoretical 116 us). This round: split the
// ij-range 2x finer (8 slices of 3 i-rows = 72 ijl each) -> grid 512 = 2 blocks/CU
// = 2 waves/SIMD, so one block's MFMAs cover the other's LDS/L2/barrier stalls.
// __launch_bounds__(256,2) caps regs at 256/wave (footprint 128 VGPR + 80 AGPR = 208).
// XCD mapping: all 8 ij-slices of an m on one XCD -> atomics L2-local; satT slice
// 8 m x 400 KB = 3.2 MB L2-resident.
// Wave w owns p-tiles {w, 4+w, 8+w, 12+w, 16+w} x 4 n-tiles. Tile 19 is a ghost:
// loads clamp to p=288, stores guarded by prow<289. All fragment loops are
// compile-time unrolled (runtime trip counts -> scratch, the round-4 bug).
// bf16x2 split: acc += ah*bh + ah*bl + al*bh.
__global__ __launch_bounds__(256, 2) void corr_mfma(const __hip_bfloat16* __restrict__ sth,
                                                    const __hip_bfloat16* __restrict__ stl,
                                                    const __hip_bfloat16* __restrict__ gth,
                                                    const __hip_bfloat16* __restrict__ gtl,
                                                    float* __restrict__ corr) {
    __shared__ __align__(16) __hip_bfloat16 B[2][2][64 * 72];  // [buf][h/l][n*72+c], 72-pad
    int bid = blockIdx.x;
    int xcd = bid & 7, slot = bid >> 3;            // slot 0..63
    int m = xcd * 8 + (slot >> 3), iq = slot & 7;  // 8 m per XCD, 8 ij-slices per m
    int tid = threadIdx.x;
    int w = tid >> 6, l = tid & 63, r = l & 15, g = l >> 4;

    int rowbase[5];
#pragma unroll
    for (int k = 0; k < 5; k++) {
        int p = 16 * (w + 4 * k) + r;
        if (p > 288) p = 288;                 // ghost rows read a valid pixel
        rowbase[k] = (p / 17) * 40 + (p % 17);
    }
    f32x4 acc[5][4];
#pragma unroll
    for (int k = 0; k < 5; k++)
#pragma unroll
        for (int nt = 0; nt < 4; nt++) acc[k][nt] = (f32x4)0.0f;

    const __hip_bfloat16* sh = sth + (size_t)m * 102400;
    const __hip_bfloat16* sl = stl + (size_t)m * 102400;
    int stn = tid >> 2, stc = (tid & 3) * 16;  // staging dest (n, c0)

#define STAGE(buf, ijl) {                                                        \
        int ijg = 72 * iq + (ijl);                                               \
        const float4* s_h = (const float4*)(gth + (size_t)ijg * 4096 + tid * 16);\
        const float4* s_l = (const float4*)(gtl + (size_t)ijg * 4096 + tid * 16);\
        float4 vh0 = s_h[0], vh1 = s_h[1], vl0 = s_l[0], vl1 = s_l[1];           \
        float4* dH = (float4*)&B[buf][0][stn * 72 + stc];                        \
        float4* dL = (float4*)&B[buf][1][stn * 72 + stc];                        \
        dH[0] = vh0; dH[1] = vh1; dL[0] = vl0; dL[1] = vl1;                      \
    }

    STAGE(0, 0);
    __syncthreads();

    for (int ijl = 0; ijl < 72; ijl++) {
        int buf = ijl & 1;
        if (ijl + 1 < 72) STAGE(buf ^ 1, ijl + 1);

        int pixoff = (3 * iq + ijl / 24) * 40 + (ijl % 24);  // i*40 + j

        short8 ah[5][2], al[5][2];
#pragma unroll
        for (int k = 0; k < 5; k++) {
            size_t e = (size_t)(rowbase[k] + pixoff) * 64 + g * 8;
            ah[k][0] = *(const short8*)(sh + e);
            ah[k][1] = *(const short8*)(sh + e + 32);
            al[k][0] = *(const short8*)(sl + e);
            al[k][1] = *(const short8*)(sl + e + 32);
        }
#pragma unroll
        for (int cc = 0; cc < 2; cc++) {
            short8 bh[4], bl[4];
#pragma unroll
            for (int nt = 0; nt < 4; nt++) {
                int off = (nt * 16 + r) * 72 + cc * 32 + g * 8;
                bh[nt] = *(const short8*)&B[buf][0][off];
                bl[nt] = *(const short8*)&B[buf][1][off];
            }
#pragma unroll
            for (int k = 0; k < 5; k++)
#pragma unroll
                for (int nt = 0; nt < 4; nt++) {
                    acc[k][nt] = __builtin_amdgcn_mfma_f32_16x16x32_bf16(ah[k][cc], bh[nt], acc[k][nt], 0, 0, 0);
                    acc[k][nt] = __builtin_amdgcn_mfma_f32_16x16x32_bf16(ah[k][cc], bl[nt], acc[k][nt], 0, 0, 0);
                    acc[k][nt] = __builtin_amdgcn_mfma_f32_16x16x32_bf16(al[k][cc], bh[nt], acc[k][nt], 0, 0, 0);
                }
        }
        __syncthreads();
    }

#pragma unroll
    for (int k = 0; k < 5; k++) {
        int tile = w + 4 * k;
#pragma unroll
        for (int nt = 0; nt < 4; nt++)
#pragma unroll
            for (int reg = 0; reg < 4; reg++) {
                int prow = 16 * tile + 4 * g + reg;
                if (prow < 289)
                    atomicAdd(&corr[((size_t)m * 304 + prow) * 64 + nt * 16 + r],
                              acc[k][nt][reg]);
            }
    }
#undef STAGE
}

// ---------- K2: argmax + similarity. grid 4096 = (m,n); block 64 ----------
__global__ __launch_bounds__(64) void argsim(const float* __restrict__ corr,
                                             const float* __restrict__ win2,
                                             const float* __restrict__ gn2,
                                             float* __restrict__ out,
                                             int* __restrict__ idxb) {
    int b = blockIdx.x, m = b >> 6, n = b & 63, lane = threadIdx.x;
    float bv = -3.0e38f;
    int bi = 1 << 30;
    for (int k = 0; k < 5; k++) {
        int p = lane + 64 * k;
        if (p < 289) {
            float v = corr[((size_t)m * 304 + p) * 64 + n];
            if (v > bv) { bv = v; bi = p; }   // ascending p: strict > = first occurrence
        }
    }
    for (int off = 32; off; off >>= 1) {
        float ov = __shfl_down(bv, off);
        int oi = __shfl_down(bi, off);
        if (ov > bv || (ov == bv && oi < bi)) { bv = ov; bi = oi; }
    }
    if (lane == 0) {
        float np = sqrtf(win2[m * 289 + bi]);
        float ng = sqrtf(gn2[n]);
        out[b] = bv / (fmaxf(np, 1e-12f) * fmaxf(ng, 1e-12f));
        idxb[b] = bi;
    }
}

// ---------- K3: winning patch for (63,63). grid 144; block 256 ----------
__global__ __launch_bounds__(256) void copy_patch(const float* __restrict__ sat,
                                                  const int* __restrict__ idxb,
                                                  float* __restrict__ out) {
    int fidx = idxb[4095];
    int hy = fidx / 17, wx = fidx % 17;
    int e = blockIdx.x * 256 + threadIdx.x;   // < 36864
    int c = e / 576;
    int rem = e - c * 576;
    int rr = rem / 24, col = rem - rr * 24;
    out[4096 + e] = sat[(size_t)(63 * 64 + c) * 4096 + (12 + hy + rr) * 64 + 12 + wx + col];
}

extern "C" void kernel_launch(void* const* d_in, const int* in_sizes, int n_in,
                              void* d_out, int out_size, void* d_ws, size_t ws_size,
                              hipStream_t stream) {
    const float* grd = (const float*)d_in[0];
    const float* sat = (const float*)d_in[1];
    float* out = (float*)d_out;

    float* wsf = (float*)d_ws;
    __hip_bfloat16* sth = (__hip_bfloat16*)(wsf + SATT_HI);
    __hip_bfloat16* stl = (__hip_bfloat16*)(wsf + SATT_LO);
    __hip_bfloat16* gth = (__hip_bfloat16*)(wsf + GRDT_HI);
    __hip_bfloat16* gtl = (__hip_bfloat16*)(wsf + GRDT_LO);
    float* corr = wsf + CORR_O;
    float* win2 = wsf + WIN2_O;
    float* gn2  = wsf + GN2_O;
    int*   idxb = (int*)(wsf + IDX_O);

    hipMemsetAsync(corr, 0, (size_t)64 * 304 * 64 * sizeof(float), stream);
    make_satT<<<2560, 256, 0, stream>>>(sat, sth, stl);
    make_grdT<<<256, 256, 0, stream>>>(grd, gth, gtl);
    make_win2<<<64, 256, 0, stream>>>(sat, win2);
    make_gn2<<<64, 256, 0, stream>>>(grd, gn2);
    corr_mfma<<<512, 256, 0, stream>>>(sth, stl, gth, gtl, corr);
    argsim<<<4096, 64, 0, stream>>>(corr, win2, gn2, out, idxb);
    copy_patch<<<144, 256, 0, stream>>>(sat, idxb, out);
}

// Round 8
// 295.410 us; speedup vs baseline: 8.8329x; 1.3958x over previous
//
#include <hip/hip_runtime.h>
#include <hip/hip_bf16.h>
#include <math.h>

// Shapes: grd (N=64,C=64,24,24), sat (M=64,C=64,64,64); crop sat[:,:,12:52,12:52] (40x40)
// corr (64,64,17,17); out: [0,4096) similarity f32, [4096,40960) sat_f (64,24,24) f32.
//
// Pipeline: satT/grdT2 bf16 hi-lo transforms -> MFMA implicit-GEMM corr (3-product
// bf16x2, fp32-class accuracy, sat window staged in LDS) -> argmax -> sim.

typedef float f32x4 __attribute__((ext_vector_type(4)));
typedef short short8 __attribute__((ext_vector_type(8)));

// ws layout (float words)
#define SATT_HI 0u          // bf16 [m][40*40 pix][64 c]
#define SATT_LO 3276800u
#define GRDT_HI 6553600u    // bf16 [ij=576][n=64][c=64]
#define GRDT_LO 7733248u
#define CORR_O  8912896u    // f32 [m][304][64]
#define WIN2_O  10158080u   // f32 [m][289]
#define GN2_O   10176576u   // f32 [64]
#define IDX_O   10176640u   // int [4096]

// ---------- T1: satT hi/lo, channel-last. grid 2560 = (m, r); block 256 ----------
__global__ __launch_bounds__(256) void make_satT(const float* __restrict__ sat,
                                                 __hip_bfloat16* __restrict__ sth,
                                                 __hip_bfloat16* __restrict__ stl) {
    __shared__ __hip_bfloat16 th[40 * 66], tl[40 * 66];
    int m = blockIdx.x / 40, r = blockIdx.x % 40;
    int tid = threadIdx.x;
    const float* base = sat + (size_t)m * 262144 + (12 + r) * 64 + 12;
    for (int k = 0; k < 10; k++) {
        int idx = tid + 256 * k;          // 2560 = 64c * 40w
        int c = idx / 40, w2 = idx % 40;
        float v = base[c * 4096 + w2];
        __hip_bfloat16 h = __float2bfloat16(v);
        __hip_bfloat16 lo = __float2bfloat16(v - __bfloat162float(h));
        th[w2 * 66 + c] = h;
        tl[w2 * 66 + c] = lo;
    }
    __syncthreads();
    __hip_bfloat16* dh = sth + (size_t)m * 102400 + r * 2560;
    __hip_bfloat16* dl = stl + (size_t)m * 102400 + r * 2560;
    for (int k = 0; k < 10; k++) {
        int idx = tid + 256 * k;          // idx = w*64 + c
        int w2 = idx >> 6, c = idx & 63;
        dh[idx] = th[w2 * 66 + c];
        dl[idx] = tl[w2 * 66 + c];
    }
}

// ---------- T2: grdT2 [ij][n][c] hi/lo. grid 256 = (n, c-half, hi/lo); block 256 ----------
__global__ __launch_bounds__(256) void make_grdT(const float* __restrict__ grd,
                                                 __hip_bfloat16* __restrict__ gth,
                                                 __hip_bfloat16* __restrict__ gtl) {
    __shared__ __hip_bfloat16 t[32 * 577];
    int bid = blockIdx.x;
    int n = bid >> 2, ch = (bid >> 1) & 1, hl = bid & 1;
    int tid = threadIdx.x;
    const float* src = grd + (size_t)n * 36864 + ch * 32 * 576;
    for (int k = 0; k < 72; k++) {
        int idx = tid + 256 * k;          // idx = cl*576 + ij
        int cl = idx / 576, ij = idx % 576;
        float v = src[idx];
        __hip_bfloat16 h = __float2bfloat16(v);
        t[cl * 577 + ij] = hl ? __float2bfloat16(v - __bfloat162float(h)) : h;
    }
    __syncthreads();
    __hip_bfloat16* dst = hl ? gtl : gth;
    for (int k = 0; k < 72; k++) {
        int idx = tid + 256 * k;          // idx = ij*32 + cl
        int ij = idx >> 5, cl = idx & 31;
        dst[(size_t)ij * 4096 + n * 64 + ch * 32 + cl] = t[cl * 577 + ij];
    }
}

// ---------- N1: patch-window norms^2 via separable sums. grid 64 (m) ----------
__global__ __launch_bounds__(256) void make_win2(const float* __restrict__ sat,
                                                 float* __restrict__ win2) {
    __shared__ float S2[40][41];
    __shared__ float RS[40][18];
    int m = blockIdx.x, tid = threadIdx.x;
    const float* base = sat + (size_t)m * 262144;
    for (int k = 0; k < 7; k++) {
        int idx = tid + 256 * k;
        if (idx < 1600) {
            int r = idx / 40, w2 = idx % 40;
            float s = 0.0f;
            for (int c = 0; c < 64; c++) {
                float v = base[c * 4096 + (12 + r) * 64 + 12 + w2];
                s += v * v;
            }
            S2[r][w2] = s;
        }
    }
    __syncthreads();
    for (int k = 0; k < 3; k++) {
        int idx = tid + 256 * k;
        if (idx < 680) {
            int r = idx / 17, x = idx % 17;
            float s = 0.0f;
            for (int j = 0; j < 24; j++) s += S2[r][x + j];
            RS[r][x] = s;
        }
    }
    __syncthreads();
    for (int k = 0; k < 2; k++) {
        int idx = tid + 256 * k;
        if (idx < 289) {
            int y = idx / 17, x = idx % 17;
            float s = 0.0f;
            for (int i2 = 0; i2 < 24; i2++) s += RS[y + i2][x];
            win2[m * 289 + idx] = s;
        }
    }
}

// ---------- N2: ||grd_n||^2. grid 64 (n) ----------
__global__ __launch_bounds__(256) void make_gn2(const float* __restrict__ grd,
                                                float* __restrict__ gn2) {
    int n = blockIdx.x, tid = threadIdx.x;
    const float* g = grd + (size_t)n * 36864;
    float s = 0.0f;
    for (int k = 0; k < 144; k++) {
        float v = g[tid + 256 * k];
        s += v * v;
    }
    for (int off = 32; off; off >>= 1) s += __shfl_down(s, off);
    __shared__ float red[4];
    if ((tid & 63) == 0) red[tid >> 6] = s;
    __syncthreads();
    if (tid == 0) gn2[n] = red[0] + red[1] + red[2] + red[3];
}

// ---------- K1: MFMA corr. grid 512; block 256 = 4 waves; 2 blocks/CU ----------
// Round-7 post-mortem: A-fragments were re-read from global every iteration
// (3 GB total from L2/L3, 96 flop/A-byte vs ~240 needed) -> A-BW-bound at
// MfmaUtil 33%. Fix: stage the block's sat window in LDS. Window for a 3-i
// slice = 19 rows x 40 cols; tile c in 2 chunks of 32 and split the hi/lo
// operand passes so only one sat array is resident:
//   satW = 19*40 pix x 32 c = 48,640 B; per c-chunk: hi-pass (ah*bh + ah*bl),
//   lo-pass (al*bh); acc persists in AGPRs across all 4 passes.
// A-global-traffic: 3 GB -> 100 MB (unique only). B rows unpadded 32 elems
// (64 B): frag reads cover 64 distinct 16-B slots/wave -> conflict-free (the
// old 72-elem pad's 144-B stride caused the 9.4M conflicts). LDS total
// 65,024 B -> 2 blocks/CU.
// Wave w owns p-tiles {w,4+w,8+w,12+w,16+w} x 4 n-tiles; tile 19 is a ghost
// (loads clamp to p=288, stores guarded). All loops compile-time unrolled.
__global__ __launch_bounds__(256, 2) void corr_mfma(const __hip_bfloat16* __restrict__ sth,
                                                    const __hip_bfloat16* __restrict__ stl,
                                                    const __hip_bfloat16* __restrict__ gth,
                                                    const __hip_bfloat16* __restrict__ gtl,
                                                    float* __restrict__ corr) {
    __shared__ __align__(16) __hip_bfloat16 satW[760 * 32];     // 48,640 B
    __shared__ __align__(16) __hip_bfloat16 Bl[2][2][64 * 32];  // [buf][h/l][n*32+c'] 16,384 B

    int bid = blockIdx.x;
    int xcd = bid & 7, slot = bid >> 3;            // slot 0..63
    int m = xcd * 8 + (slot >> 3), iq = slot & 7;  // 8 m per XCD, 8 i-slices per m
    int tid = threadIdx.x;
    int w = tid >> 6, l = tid & 63, r = l & 15, g = l >> 4;

    int rowbase[5];
#pragma unroll
    for (int k = 0; k < 5; k++) {
        int p = 16 * (w + 4 * k) + r;
        if (p > 288) p = 288;                 // ghost rows read a valid pixel
        rowbase[k] = (p / 17) * 40 + (p % 17);
    }
    f32x4 acc[5][4];
#pragma unroll
    for (int k = 0; k < 5; k++)
#pragma unroll
        for (int nt = 0; nt < 4; nt++) acc[k][nt] = (f32x4)0.0f;

    // satT source: [m][pix][64c]; window pixel wp (0..759) -> global pix R0*40+wp,
    // R0 = 3*iq -> elem offset m*102400 + iq*7680 + wp*64 (+cc*32).
    const __hip_bfloat16* sat_hi = sth + (size_t)m * 102400 + iq * 7680;
    const __hip_bfloat16* sat_lo = stl + (size_t)m * 102400 + iq * 7680;
    // B source: gth/gtl [ijg][n*64+c]; ijg = iq*72 + ijl.
    size_t bbase = (size_t)(iq * 72) * 4096 + (tid >> 2) * 64 + (tid & 3) * 8;

    // satW stage: 3040 16-B slots; idx -> pix=idx>>2, seg=idx&3; dst byte idx*16.
#define STAGE_SAT(SRC, CC) {                                                   \
        const __hip_bfloat16* sp_ = (SRC) + (CC) * 32;                         \
        _Pragma("unroll")                                                      \
        for (int k2 = 0; k2 < 12; k2++) {                                      \
            int idx = tid + 256 * k2;                                          \
            if (idx < 3040) {                                                  \
                float4 v = *(const float4*)(sp_ + (idx >> 2) * 64 + (idx & 3) * 8); \
                *(float4*)((char*)satW + (size_t)idx * 16) = v;                \
            }                                                                  \
        }                                                                      \
    }
    // B stage: thread t -> n=t>>2, seg=t&3; dst byte t*16 (linear, conflict-free).
#define STAGE_B2(BUF, IJL, CC) {                                               \
        size_t so_ = bbase + (size_t)(IJL) * 4096 + (CC) * 32;                 \
        float4 vh_ = *(const float4*)(gth + so_);                              \
        float4 vl_ = *(const float4*)(gtl + so_);                              \
        *(float4*)((char*)&Bl[BUF][0][0] + tid * 16) = vh_;                    \
        *(float4*)((char*)&Bl[BUF][1][0] + tid * 16) = vl_;                    \
    }
#define STAGE_B1(BUF, IJL, CC) {                                               \
        size_t so_ = bbase + (size_t)(IJL) * 4096 + (CC) * 32;                 \
        float4 vh_ = *(const float4*)(gth + so_);                              \
        *(float4*)((char*)&Bl[BUF][0][0] + tid * 16) = vh_;                    \
    }

    for (int cc = 0; cc < 2; cc++) {
        // ================= hi pass: acc += ah*bh + ah*bl =================
        STAGE_SAT(sat_hi, cc);
        STAGE_B2(0, 0, cc);
        __syncthreads();
        for (int ijl = 0; ijl < 72; ijl++) {
            int buf = ijl & 1;
            if (ijl + 1 < 72) STAGE_B2(buf ^ 1, ijl + 1, cc);
            int il = ijl / 24, jj = ijl - il * 24;
            int pixoff = il * 40 + jj;

            short8 a0[5];
#pragma unroll
            for (int k = 0; k < 5; k++)
                a0[k] = *(const short8*)&satW[(rowbase[k] + pixoff) * 32 + g * 8];
            short8 bh[4], bl4[4];
#pragma unroll
            for (int nt = 0; nt < 4; nt++) {
                int off = (nt * 16 + r) * 32 + g * 8;
                bh[nt]  = *(const short8*)&Bl[buf][0][off];
                bl4[nt] = *(const short8*)&Bl[buf][1][off];
            }
#pragma unroll
            for (int k = 0; k < 5; k++)
#pragma unroll
                for (int nt = 0; nt < 4; nt++) {
                    acc[k][nt] = __builtin_amdgcn_mfma_f32_16x16x32_bf16(a0[k], bh[nt], acc[k][nt], 0, 0, 0);
                    acc[k][nt] = __builtin_amdgcn_mfma_f32_16x16x32_bf16(a0[k], bl4[nt], acc[k][nt], 0, 0, 0);
                }
            __syncthreads();
        }
        // ================= lo pass: acc += al*bh =================
        STAGE_SAT(sat_lo, cc);
        STAGE_B1(0, 0, cc);
        __syncthreads();
        for (int ijl = 0; ijl < 72; ijl++) {
            int buf = ijl & 1;
            if (ijl + 1 < 72) STAGE_B1(buf ^ 1, ijl + 1, cc);
            int il = ijl / 24, jj = ijl - il * 24;
            int pixoff = il * 40 + jj;

            short8 a0[5];
#pragma unroll
            for (int k = 0; k < 5; k++)
                a0[k] = *(const short8*)&satW[(rowbase[k] + pixoff) * 32 + g * 8];
            short8 bh[4];
#pragma unroll
            for (int nt = 0; nt < 4; nt++)
                bh[nt] = *(const short8*)&Bl[buf][0][(nt * 16 + r) * 32 + g * 8];
#pragma unroll
            for (int k = 0; k < 5; k++)
#pragma unroll
                for (int nt = 0; nt < 4; nt++)
                    acc[k][nt] = __builtin_amdgcn_mfma_f32_16x16x32_bf16(a0[k], bh[nt], acc[k][nt], 0, 0, 0);
            __syncthreads();
        }
    }

#pragma unroll
    for (int k = 0; k < 5; k++) {
        int tile = w + 4 * k;
#pragma unroll
        for (int nt = 0; nt < 4; nt++)
#pragma unroll
            for (int reg = 0; reg < 4; reg++) {
                int prow = 16 * tile + 4 * g + reg;
                if (prow < 289)
                    atomicAdd(&corr[((size_t)m * 304 + prow) * 64 + nt * 16 + r],
                              acc[k][nt][reg]);
            }
    }
#undef STAGE_SAT
#undef STAGE_B2
#undef STAGE_B1
}

// ---------- K2: argmax + similarity. grid 4096 = (m,n); block 64 ----------
__global__ __launch_bounds__(64) void argsim(const float* __restrict__ corr,
                                             const float* __restrict__ win2,
                                             const float* __restrict__ gn2,
                                             float* __restrict__ out,
                                             int* __restrict__ idxb) {
    int b = blockIdx.x, m = b >> 6, n = b & 63, lane = threadIdx.x;
    float bv = -3.0e38f;
    int bi = 1 << 30;
    for (int k = 0; k < 5; k++) {
        int p = lane + 64 * k;
        if (p < 289) {
            float v = corr[((size_t)m * 304 + p) * 64 + n];
            if (v > bv) { bv = v; bi = p; }   // ascending p: strict > = first occurrence
        }
    }
    for (int off = 32; off; off >>= 1) {
        float ov = __shfl_down(bv, off);
        int oi = __shfl_down(bi, off);
        if (ov > bv || (ov == bv && oi < bi)) { bv = ov; bi = oi; }
    }
    if (lane == 0) {
        float np = sqrtf(win2[m * 289 + bi]);
        float ng = sqrtf(gn2[n]);
        out[b] = bv / (fmaxf(np, 1e-12f) * fmaxf(ng, 1e-12f));
        idxb[b] = bi;
    }
}

// ---------- K3: winning patch for (63,63). grid 144; block 256 ----------
__global__ __launch_bounds__(256) void copy_patch(const float* __restrict__ sat,
                                                  const int* __restrict__ idxb,
                                                  float* __restrict__ out) {
    int fidx = idxb[4095];
    int hy = fidx / 17, wx = fidx % 17;
    int e = blockIdx.x * 256 + threadIdx.x;   // < 36864
    int c = e / 576;
    int rem = e - c * 576;
    int rr = rem / 24, col = rem - rr * 24;
    out[4096 + e] = sat[(size_t)(63 * 64 + c) * 4096 + (12 + hy + rr) * 64 + 12 + wx + col];
}

extern "C" void kernel_launch(void* const* d_in, const int* in_sizes, int n_in,
                              void* d_out, int out_size, void* d_ws, size_t ws_size,
                              hipStream_t stream) {
    const float* grd = (const float*)d_in[0];
    const float* sat = (const float*)d_in[1];
    float* out = (float*)d_out;

    float* wsf = (float*)d_ws;
    __hip_bfloat16* sth = (__hip_bfloat16*)(wsf + SATT_HI);
    __hip_bfloat16* stl = (__hip_bfloat16*)(wsf + SATT_LO);
    __hip_bfloat16* gth = (__hip_bfloat16*)(wsf + GRDT_HI);
    __hip_bfloat16* gtl = (__hip_bfloat16*)(wsf + GRDT_LO);
    float* corr = wsf + CORR_O;
    float* win2 = wsf + WIN2_O;
    float* gn2  = wsf + GN2_O;
    int*   idxb = (int*)(wsf + IDX_O);

    hipMemsetAsync(corr, 0, (size_t)64 * 304 * 64 * sizeof(float), stream);
    make_satT<<<2560, 256, 0, stream>>>(sat, sth, stl);
    make_grdT<<<256, 256, 0, stream>>>(grd, gth, gtl);
    make_win2<<<64, 256, 0, stream>>>(sat, win2);
    make_gn2<<<64, 256, 0, stream>>>(grd, gn2);
    corr_mfma<<<512, 256, 0, stream>>>(sth, stl, gth, gtl, corr);
    argsim<<<4096, 64, 0, stream>>>(corr, win2, gn2, out, idxb);
    copy_patch<<<144, 256, 0, stream>>>(sat, idxb, out);
}

// Round 9
// 287.433 us; speedup vs baseline: 9.0780x; 1.0277x over previous
//
#include <hip/hip_runtime.h>
#include <hip/hip_bf16.h>
#include <math.h>

// Shapes: grd (N=64,C=64,24,24), sat (M=64,C=64,64,64); crop sat[:,:,12:52,12:52] (40x40)
// corr (64,64,17,17); out: [0,4096) similarity f32, [4096,40960) sat_f (64,24,24) f32.
//
// Pipeline: satT/grdT2 bf16 hi-lo transforms -> MFMA implicit-GEMM corr (3-product
// bf16x2, fp32-class accuracy, sat window staged in LDS, XOR-bank-swizzled) ->
// argmax -> sim from corr_max and precomputed norms.

typedef float f32x4 __attribute__((ext_vector_type(4)));
typedef short short8 __attribute__((ext_vector_type(8)));

// ws layout (float words)
#define SATT_HI 0u          // bf16 [m][40*40 pix][64 c]
#define SATT_LO 3276800u
#define GRDT_HI 6553600u    // bf16 [ij=576][n=64][c=64]
#define GRDT_LO 7733248u
#define CORR_O  8912896u    // f32 [m][304][64]
#define WIN2_O  10158080u   // f32 [m][289]
#define GN2_O   10176576u   // f32 [64]
#define IDX_O   10176640u   // int [4096]

// LDS bank swizzle: rows are 64 B apart, so chunk (addr>>4)&7 only took values
// {g, g+4} across 16 consecutive rows -> 8-way conflict (round-8: 31.85M).
// XOR the chunk bits with the row-parity bits: bijective involution, 2-way max.
#define SWZ(off) ((off) ^ ((((off) >> 7) & 7) << 4))

// ---------- T1: satT hi/lo, channel-last. grid 2560 = (m, r); block 256 ----------
__global__ __launch_bounds__(256) void make_satT(const float* __restrict__ sat,
                                                 __hip_bfloat16* __restrict__ sth,
                                                 __hip_bfloat16* __restrict__ stl) {
    __shared__ __hip_bfloat16 th[40 * 66], tl[40 * 66];
    int m = blockIdx.x / 40, r = blockIdx.x % 40;
    int tid = threadIdx.x;
    const float* base = sat + (size_t)m * 262144 + (12 + r) * 64 + 12;
    for (int k = 0; k < 10; k++) {
        int idx = tid + 256 * k;          // 2560 = 64c * 40w
        int c = idx / 40, w2 = idx % 40;
        float v = base[c * 4096 + w2];
        __hip_bfloat16 h = __float2bfloat16(v);
        __hip_bfloat16 lo = __float2bfloat16(v - __bfloat162float(h));
        th[w2 * 66 + c] = h;
        tl[w2 * 66 + c] = lo;
    }
    __syncthreads();
    __hip_bfloat16* dh = sth + (size_t)m * 102400 + r * 2560;
    __hip_bfloat16* dl = stl + (size_t)m * 102400 + r * 2560;
    for (int k = 0; k < 10; k++) {
        int idx = tid + 256 * k;          // idx = w*64 + c
        int w2 = idx >> 6, c = idx & 63;
        dh[idx] = th[w2 * 66 + c];
        dl[idx] = tl[w2 * 66 + c];
    }
}

// ---------- T2: grdT2 [ij][n][c] hi/lo. grid 256 = (n, c-half, hi/lo); block 256 ----------
__global__ __launch_bounds__(256) void make_grdT(const float* __restrict__ grd,
                                                 __hip_bfloat16* __restrict__ gth,
                                                 __hip_bfloat16* __restrict__ gtl) {
    __shared__ __hip_bfloat16 t[32 * 577];
    int bid = blockIdx.x;
    int n = bid >> 2, ch = (bid >> 1) & 1, hl = bid & 1;
    int tid = threadIdx.x;
    const float* src = grd + (size_t)n * 36864 + ch * 32 * 576;
    for (int k = 0; k < 72; k++) {
        int idx = tid + 256 * k;          // idx = cl*576 + ij
        int cl = idx / 576, ij = idx % 576;
        float v = src[idx];
        __hip_bfloat16 h = __float2bfloat16(v);
        t[cl * 577 + ij] = hl ? __float2bfloat16(v - __bfloat162float(h)) : h;
    }
    __syncthreads();
    __hip_bfloat16* dst = hl ? gtl : gth;
    for (int k = 0; k < 72; k++) {
        int idx = tid + 256 * k;          // idx = ij*32 + cl
        int ij = idx >> 5, cl = idx & 31;
        dst[(size_t)ij * 4096 + n * 64 + ch * 32 + cl] = t[cl * 577 + ij];
    }
}

// ---------- N1: patch-window norms^2 via separable sums. grid 64 (m) ----------
__global__ __launch_bounds__(256) void make_win2(const float* __restrict__ sat,
                                                 float* __restrict__ win2) {
    __shared__ float S2[40][41];
    __shared__ float RS[40][18];
    int m = blockIdx.x, tid = threadIdx.x;
    const float* base = sat + (size_t)m * 262144;
    for (int k = 0; k < 7; k++) {
        int idx = tid + 256 * k;
        if (idx < 1600) {
            int r = idx / 40, w2 = idx % 40;
            float s = 0.0f;
            for (int c = 0; c < 64; c++) {
                float v = base[c * 4096 + (12 + r) * 64 + 12 + w2];
                s += v * v;
            }
            S2[r][w2] = s;
        }
    }
    __syncthreads();
    for (int k = 0; k < 3; k++) {
        int idx = tid + 256 * k;
        if (idx < 680) {
            int r = idx / 17, x = idx % 17;
            float s = 0.0f;
            for (int j = 0; j < 24; j++) s += S2[r][x + j];
            RS[r][x] = s;
        }
    }
    __syncthreads();
    for (int k = 0; k < 2; k++) {
        int idx = tid + 256 * k;
        if (idx < 289) {
            int y = idx / 17, x = idx % 17;
            float s = 0.0f;
            for (int i2 = 0; i2 < 24; i2++) s += RS[y + i2][x];
            win2[m * 289 + idx] = s;
        }
    }
}

// ---------- N2: ||grd_n||^2. grid 64 (n) ----------
__global__ __launch_bounds__(256) void make_gn2(const float* __restrict__ grd,
                                                float* __restrict__ gn2) {
    int n = blockIdx.x, tid = threadIdx.x;
    const float* g = grd + (size_t)n * 36864;
    float s = 0.0f;
    for (int k = 0; k < 144; k++) {
        float v = g[tid + 256 * k];
        s += v * v;
    }
    for (int off = 32; off; off >>= 1) s += __shfl_down(s, off);
    __shared__ float red[4];
    if ((tid & 63) == 0) red[tid >> 6] = s;
    __syncthreads();
    if (tid == 0) gn2[n] = red[0] + red[1] + red[2] + red[3];
}

// ---------- K1: MFMA corr. grid 512; block 256 = 4 waves; 2 blocks/CU ----------
// Round-8 post-mortem: staging fixed the A-BW wall (256 us, MfmaUtil 50.5%) but
// both fragment-read patterns stride 64 B across the 16 r-lanes -> 8-way bank
// conflict (31.85M) -> LDS pipe at ~2.9x cost, co-critical with MFMA. This round:
// SWZ() XOR-swizzle on ALL satW/Bl accesses (write+read, same involution) ->
// every 16-consecutive-row access lands 2x per chunk = free.
// Structure: satW = 19 rows x 40 cols x 32 c (one c-chunk, one of hi/lo) staged
// per pass; per c-chunk: hi-pass (ah*bh + ah*bl), lo-pass (al*bh); acc persists
// in AGPRs. Wave w owns p-tiles {w,4+w,8+w,12+w,16+w} x 4 n-tiles; tile 19 is a
// ghost (loads clamp, stores guarded). All fragment loops compile-time unrolled.
__global__ __launch_bounds__(256, 2) void corr_mfma(const __hip_bfloat16* __restrict__ sth,
                                                    const __hip_bfloat16* __restrict__ stl,
                                                    const __hip_bfloat16* __restrict__ gth,
                                                    const __hip_bfloat16* __restrict__ gtl,
                                                    float* __restrict__ corr) {
    __shared__ __align__(16) __hip_bfloat16 satW[760 * 32];     // 48,640 B
    __shared__ __align__(16) __hip_bfloat16 Bl[2][2][64 * 32];  // [buf][h/l], 4096 B each

    int bid = blockIdx.x;
    int xcd = bid & 7, slot = bid >> 3;            // slot 0..63
    int m = xcd * 8 + (slot >> 3), iq = slot & 7;  // 8 m per XCD, 8 i-slices per m
    int tid = threadIdx.x;
    int w = tid >> 6, l = tid & 63, r = l & 15, g = l >> 4;

    int rowbase[5];
#pragma unroll
    for (int k = 0; k < 5; k++) {
        int p = 16 * (w + 4 * k) + r;
        if (p > 288) p = 288;                 // ghost rows read a valid pixel
        rowbase[k] = (p / 17) * 40 + (p % 17);
    }
    f32x4 acc[5][4];
#pragma unroll
    for (int k = 0; k < 5; k++)
#pragma unroll
        for (int nt = 0; nt < 4; nt++) acc[k][nt] = (f32x4)0.0f;

    // satT source: [m][pix][64c]; window pixel wp (0..759) -> elem offset
    // m*102400 + iq*7680 + wp*64 (+cc*32).
    const __hip_bfloat16* sat_hi = sth + (size_t)m * 102400 + iq * 7680;
    const __hip_bfloat16* sat_lo = stl + (size_t)m * 102400 + iq * 7680;
    // B source: gth/gtl [ijg][n*64+c]; ijg = iq*72 + ijl.
    size_t bbase = (size_t)(iq * 72) * 4096 + (tid >> 2) * 64 + (tid & 3) * 8;

    // Precomputed swizzled offsets (per-thread constants):
    int bdst = SWZ(tid * 16);                 // B stage dest within each 4096-B subarray
    int boff[4];                              // B frag read offsets
#pragma unroll
    for (int nt = 0; nt < 4; nt++) {
        int o = (nt * 16 + r) * 64 + g * 16;
        boff[nt] = SWZ(o);
    }

    // satW stage: 3040 16-B slots; idx -> pix=idx>>2, seg=idx&3; dst = SWZ(idx*16).
#define STAGE_SAT(SRC, CC) {                                                   \
        const __hip_bfloat16* sp_ = (SRC) + (CC) * 32;                         \
        _Pragma("unroll")                                                      \
        for (int k2 = 0; k2 < 12; k2++) {                                      \
            int idx = tid + 256 * k2;                                          \
            if (idx < 3040) {                                                  \
                float4 v = *(const float4*)(sp_ + (idx >> 2) * 64 + (idx & 3) * 8); \
                *(float4*)((char*)satW + SWZ(idx * 16)) = v;                   \
            }                                                                  \
        }                                                                      \
    }
#define STAGE_B2(BUF, IJL, CC) {                                               \
        size_t so_ = bbase + (size_t)(IJL) * 4096 + (CC) * 32;                 \
        float4 vh_ = *(const float4*)(gth + so_);                              \
        float4 vl_ = *(const float4*)(gtl + so_);                              \
        *(float4*)((char*)&Bl[BUF][0][0] + bdst) = vh_;                        \
        *(float4*)((char*)&Bl[BUF][1][0] + bdst) = vl_;                        \
    }
#define STAGE_B1(BUF, IJL, CC) {                                               \
        size_t so_ = bbase + (size_t)(IJL) * 4096 + (CC) * 32;                 \
        float4 vh_ = *(const float4*)(gth + so_);                              \
        *(float4*)((char*)&Bl[BUF][0][0] + bdst) = vh_;                        \
    }

    for (int cc = 0; cc < 2; cc++) {
        // ================= hi pass: acc += ah*bh + ah*bl =================
        STAGE_SAT(sat_hi, cc);
        STAGE_B2(0, 0, cc);
        __syncthreads();
        for (int ijl = 0; ijl < 72; ijl++) {
            int buf = ijl & 1;
            if (ijl + 1 < 72) STAGE_B2(buf ^ 1, ijl + 1, cc);
            int il = ijl / 24, jj = ijl - il * 24;
            int pixoff = il * 40 + jj;

            short8 a0[5];
#pragma unroll
            for (int k = 0; k < 5; k++) {
                int ao = (rowbase[k] + pixoff) * 64 + g * 16;
                a0[k] = *(const short8*)((const char*)satW + SWZ(ao));
            }
            short8 bh[4], bl4[4];
#pragma unroll
            for (int nt = 0; nt < 4; nt++) {
                bh[nt]  = *(const short8*)((const char*)&Bl[buf][0][0] + boff[nt]);
                bl4[nt] = *(const short8*)((const char*)&Bl[buf][1][0] + boff[nt]);
            }
#pragma unroll
            for (int k = 0; k < 5; k++)
#pragma unroll
                for (int nt = 0; nt < 4; nt++) {
                    acc[k][nt] = __builtin_amdgcn_mfma_f32_16x16x32_bf16(a0[k], bh[nt], acc[k][nt], 0, 0, 0);
                    acc[k][nt] = __builtin_amdgcn_mfma_f32_16x16x32_bf16(a0[k], bl4[nt], acc[k][nt], 0, 0, 0);
                }
            __syncthreads();
        }
        // ================= lo pass: acc += al*bh =================
        STAGE_SAT(sat_lo, cc);
        STAGE_B1(0, 0, cc);
        __syncthreads();
        for (int ijl = 0; ijl < 72; ijl++) {
            int buf = ijl & 1;
            if (ijl + 1 < 72) STAGE_B1(buf ^ 1, ijl + 1, cc);
            int il = ijl / 24, jj = ijl - il * 24;
            int pixoff = il * 40 + jj;

            short8 a0[5];
#pragma unroll
            for (int k = 0; k < 5; k++) {
                int ao = (rowbase[k] + pixoff) * 64 + g * 16;
                a0[k] = *(const short8*)((const char*)satW + SWZ(ao));
            }
            short8 bh[4];
#pragma unroll
            for (int nt = 0; nt < 4; nt++)
                bh[nt] = *(const short8*)((const char*)&Bl[buf][0][0] + boff[nt]);
#pragma unroll
            for (int k = 0; k < 5; k++)
#pragma unroll
                for (int nt = 0; nt < 4; nt++)
                    acc[k][nt] = __builtin_amdgcn_mfma_f32_16x16x32_bf16(a0[k], bh[nt], acc[k][nt], 0, 0, 0);
            __syncthreads();
        }
    }

#pragma unroll
    for (int k = 0; k < 5; k++) {
        int tile = w + 4 * k;
#pragma unroll
        for (int nt = 0; nt < 4; nt++)
#pragma unroll
            for (int reg = 0; reg < 4; reg++) {
                int prow = 16 * tile + 4 * g + reg;
                if (prow < 289)
                    atomicAdd(&corr[((size_t)m * 304 + prow) * 64 + nt * 16 + r],
                              acc[k][nt][reg]);
            }
    }
#undef STAGE_SAT
#undef STAGE_B2
#undef STAGE_B1
}

// ---------- K2: argmax + similarity. grid 4096 = (m,n); block 64 ----------
__global__ __launch_bounds__(64) void argsim(const float* __restrict__ corr,
                                             const float* __restrict__ win2,
                                             const float* __restrict__ gn2,
                                             float* __restrict__ out,
                                             int* __restrict__ idxb) {
    int b = blockIdx.x, m = b >> 6, n = b & 63, lane = threadIdx.x;
    float bv = -3.0e38f;
    int bi = 1 << 30;
    for (int k = 0; k < 5; k++) {
        int p = lane + 64 * k;
        if (p < 289) {
            float v = corr[((size_t)m * 304 + p) * 64 + n];
            if (v > bv) { bv = v; bi = p; }   // ascending p: strict > = first occurrence
        }
    }
    for (int off = 32; off; off >>= 1) {
        float ov = __shfl_down(bv, off);
        int oi = __shfl_down(bi, off);
        if (ov > bv || (ov == bv && oi < bi)) { bv = ov; bi = oi; }
    }
    if (lane == 0) {
        float np = sqrtf(win2[m * 289 + bi]);
        float ng = sqrtf(gn2[n]);
        out[b] = bv / (fmaxf(np, 1e-12f) * fmaxf(ng, 1e-12f));
        idxb[b] = bi;
    }
}

// ---------- K3: winning patch for (63,63). grid 144; block 256 ----------
__global__ __launch_bounds__(256) void copy_patch(const float* __restrict__ sat,
                                                  const int* __restrict__ idxb,
                                                  float* __restrict__ out) {
    int fidx = idxb[4095];
    int hy = fidx / 17, wx = fidx % 17;
    int e = blockIdx.x * 256 + threadIdx.x;   // < 36864
    int c = e / 576;
    int rem = e - c * 576;
    int rr = rem / 24, col = rem - rr * 24;
    out[4096 + e] = sat[(size_t)(63 * 64 + c) * 4096 + (12 + hy + rr) * 64 + 12 + wx + col];
}

extern "C" void kernel_launch(void* const* d_in, const int* in_sizes, int n_in,
                              void* d_out, int out_size, void* d_ws, size_t ws_size,
                              hipStream_t stream) {
    const float* grd = (const float*)d_in[0];
    const float* sat = (const float*)d_in[1];
    float* out = (float*)d_out;

    float* wsf = (float*)d_ws;
    __hip_bfloat16* sth = (__hip_bfloat16*)(wsf + SATT_HI);
    __hip_bfloat16* stl = (__hip_bfloat16*)(wsf + SATT_LO);
    __hip_bfloat16* gth = (__hip_bfloat16*)(wsf + GRDT_HI);
    __hip_bfloat16* gtl = (__hip_bfloat16*)(wsf + GRDT_LO);
    float* corr = wsf + CORR_O;
    float* win2 = wsf + WIN2_O;
    float* gn2  = wsf + GN2_O;
    int*   idxb = (int*)(wsf + IDX_O);

    hipMemsetAsync(corr, 0, (size_t)64 * 304 * 64 * sizeof(float), stream);
    make_satT<<<2560, 256, 0, stream>>>(sat, sth, stl);
    make_grdT<<<256, 256, 0, stream>>>(grd, gth, gtl);
    make_win2<<<64, 256, 0, stream>>>(sat, win2);
    make_gn2<<<64, 256, 0, stream>>>(grd, gn2);
    corr_mfma<<<512, 256, 0, stream>>>(sth, stl, gth, gtl, corr);
    argsim<<<4096, 64, 0, stream>>>(corr, win2, gn2, out, idxb);
    copy_patch<<<144, 256, 0, stream>>>(sat, idxb, out);
}